// Round 5
// baseline (264.857 us; speedup 1.0000x reference)
//
#include <hip/hip_runtime.h>
#include <hip/hip_bf16.h>

// y = x @ W^T, W strictly diagonal -> y[t,j] = x[t,j] * W[j,j] (exact).
//
// R4: direction-specialized producer/consumer. Prior rounds (2.1/2.3/2.5 TB/s
// across 3 structures) all had every wave alternating load-burst/store-burst
// in lockstep -> machine-wide read/write phase oscillation. Harness fill
// kernel (write-only) hits 6.7 TB/s on this box. Here: waves 0-1 of each
// block ONLY read x (global->LDS, continuous read stream), waves 2-3 ONLY
// scale+write y (LDS->global, continuous write stream), double-buffered
// through 32 KiB LDS. Diag compacted once into d_ws.

typedef float nf4 __attribute__((ext_vector_type(4)));

constexpr int N_FEAT   = 4096;
constexpr int NVEC_ROW = N_FEAT / 4;      // 1024 nf4 per row
constexpr int TOKENS_  = 8192;
constexpr int STAGES   = 8;               // rows per block
constexpr int BLOCKS   = TOKENS_ / STAGES; // 1024 blocks = 4/CU, LDS 32 KiB each

// Kernel A: compact diag(W) -> contiguous float[4096] in workspace.
__global__ __launch_bounds__(256)
void diag_compact_kernel(const float* __restrict__ W,
                         float* __restrict__ diag) {
    int j = blockIdx.x * 256 + threadIdx.x;   // 16 x 256 = 4096
    diag[j] = W[(long)j * (N_FEAT + 1)];
}

// Kernel B: producer/consumer streaming scale.
__global__ __launch_bounds__(256)
void diag_stream_kernel(const nf4* __restrict__ x,
                        const nf4* __restrict__ cdiag,   // contiguous 16 KiB
                        nf4* __restrict__ y) {
    __shared__ nf4 buf[2][NVEC_ROW];          // 2 x 16 KiB double buffer
    const int  tid    = threadIdx.x;
    const bool reader = (tid < 128);          // waves 0-1 read, waves 2-3 write
    const long row0   = (long)blockIdx.x * STAGES;

    // Writers: per-thread diag fragments are column-periodic -> fixed across
    // all stages. 8 x 16B coalesced loads from the shared 16 KiB array.
    nf4 dreg[8];
    if (!reader) {
        const int wtid = tid - 128;
#pragma unroll
        for (int k = 0; k < 8; ++k) dreg[k] = cdiag[k * 128 + wtid];
    }

    int p = 0;
    // Prologue: readers fill buf[0] with row 0.
    if (reader) {
        const long base = row0 * NVEC_ROW;
        nf4 t[8];
#pragma unroll
        for (int j = 0; j < 8; ++j) t[j] = x[base + j * 128 + tid];
#pragma unroll
        for (int j = 0; j < 8; ++j) buf[0][j * 128 + tid] = t[j];
    }
    __syncthreads();

    for (int s = 0; s < STAGES; ++s) {
        if (reader) {
            if (s + 1 < STAGES) {             // prefetch next row into buf[p^1]
                const long base = (row0 + s + 1) * NVEC_ROW;
                nf4 t[8];
#pragma unroll
                for (int j = 0; j < 8; ++j) t[j] = x[base + j * 128 + tid];
#pragma unroll
                for (int j = 0; j < 8; ++j) buf[p ^ 1][j * 128 + tid] = t[j];
            }
        } else {                              // consume buf[p] -> y row s
            const int  wtid = tid - 128;
            const long base = (row0 + s) * NVEC_ROW;
            nf4 v[8];
#pragma unroll
            for (int k = 0; k < 8; ++k) v[k] = buf[p][k * 128 + wtid];
#pragma unroll
            for (int k = 0; k < 8; ++k) y[base + k * 128 + wtid] = v[k] * dreg[k];
        }
        __syncthreads();
        p ^= 1;
    }
}

extern "C" void kernel_launch(void* const* d_in, const int* in_sizes, int n_in,
                              void* d_out, int out_size, void* d_ws, size_t ws_size,
                              hipStream_t stream) {
    const nf4*   x = (const nf4*)d_in[0];     // [8192, 4096] f32
    const float* W = (const float*)d_in[1];   // [4096, 4096] f32, diagonal
    nf4*   y    = (nf4*)d_out;                // [8192, 4096] f32
    float* diag = (float*)d_ws;               // 16 KiB scratch

    diag_compact_kernel<<<N_FEAT / 256, 256, 0, stream>>>(W, diag);
    diag_stream_kernel<<<BLOCKS, 256, 0, stream>>>(x, (const nf4*)diag, y);
}